// Round 7
// baseline (1932.801 us; speedup 1.0000x reference)
//
#include <hip/hip_runtime.h>
#include <cstdint>
#include <cstddef>

typedef __attribute__((ext_vector_type(8))) short short8;
typedef __attribute__((ext_vector_type(4))) float f32x4;

#define MFMA16(a, b, c) __builtin_amdgcn_mfma_f32_16x16x32_bf16((a), (b), (c), 0, 0, 0)

constexpr int kB = 512, kS = 256, kI = 12, kH = 256, kA = 9;
constexpr int kNS = 8;    // slices per btile (32 h-units each)
constexpr int kNB = 32;   // btiles (16 rows each)
constexpr int kT  = 512;  // 8 waves
constexpr int LDH = 264;  // padded LDS stride (bf16) for K=256 operand tiles
constexpr int kBH = kB * kH;

// d_out layout (floats): [logits 512*9][h0 512*256][h1 512*256][c0 512*256][c1 512*256]
constexpr int OUT_H = kB * kA;              // 4608
constexpr int OUT_C = OUT_H + 2 * kBH;      // 266752

__device__ __forceinline__ short f2bf(float f) {  // RTNE fp32 -> bf16 bits
  uint32_t u = __float_as_uint(f);
  u += 0x7fffu + ((u >> 16) & 1u);
  return (short)(u >> 16);
}
__device__ __forceinline__ float fast_sigmoid(float v) {
  return __builtin_amdgcn_rcpf(1.f + __expf(-v));
}
__device__ __forceinline__ float fast_tanh(float v) {
  return 2.f * __builtin_amdgcn_rcpf(1.f + __expf(-2.f * v)) - 1.f;
}

// R11 == R10 (wave-role specialization) + escalating spin backoff.
// R10's bench died with "container failed twice" (no kernel diagnostics).
// Re-audit found no deadlock: parity-buffer init chain is covered (phase-0
// gather writes hAb[1]/hBb[1] from memset/phase-0-produced exchange data),
// flag protocol is acyclic, 1 block/CU residency guaranteed (75KB LDS).
// Hardening: bounded-rate spin (s_sleep escalation) in case rocprof
// counter-replay serialization makes producers pathologically slow (R1/R3
// profiles showed 32-41ms outlier dispatches of the known-good kernel).
//
// Structure:
//   wave = (L=wave>>2, U=(wave>>1)&1, R=wave&1)
//   L0R0: emb(p+2) gen + z(p+1)=emb@w_ih0 prefold -> gZ   (prefetchable)
//   L1R0: hB(h1(p-2))@w_hh1 partial -> gP                  (same-phase)
//   L0R1: hA@w_hh0 partial; +gZ[par]; elem L0 IN-REGISTER  (C-frag holds
//   L1R1: hA@w_ih1 partial; +gP;      elem L1 IN-REGISTER   all 4 gates)
// -> no gate LDS round-trip, 2 barriers/phase, per-CU A-frag reads
//    192->64 b128. After B_mid: R1 combine+elem+store+publish while R0
//    CONCURRENTLY spin+gather next h into [par^1] buffers.
__global__ __launch_bounds__(kT) void lstm_scan_kernel(
    const float* __restrict__ x,
    const float* __restrict__ W_emb, const float* __restrict__ b_emb,
    const float* __restrict__ w_ih0, const float* __restrict__ w_hh0,
    const float* __restrict__ b_ih0, const float* __restrict__ b_hh0,
    const float* __restrict__ w_ih1, const float* __restrict__ w_hh1,
    const float* __restrict__ b_ih1, const float* __restrict__ b_hh1,
    unsigned short* __restrict__ h0ex, unsigned short* __restrict__ h1ex,
    unsigned char* __restrict__ flags,
    float* __restrict__ dout)
{
  const int tid   = threadIdx.x;
  const int btile = blockIdx.x & (kNB - 1);  // bid%8==btile%8 -> btile stays on one XCD
  const int slice = blockIdx.x >> 5;
  const int b0    = btile * 16;
  const int lane  = tid & 63;
  const int wave  = tid >> 6;
  const int n16   = lane & 15;
  const int quad  = lane >> 4;
  const int L     = wave >> 2;        // layer
  const int U     = (wave >> 1) & 1;  // unit-group (16 units)
  const int R     = wave & 1;         // role

  __shared__ short embL[2][16 * LDH];  // emb(t) A-operand, parity-buffered
  __shared__ short hAb[2][16 * LDH];   // h0(p-1), parity-buffered
  __shared__ short hBb[2][16 * LDH];   // h1(p-2), parity-buffered
  __shared__ float gZ[2 * 2 * 4 * 256];  // [par][U][tile][lane*4+r] z partial
  __shared__ float gP[2 * 4 * 256];      // [U][tile][lane*4+r] hB partial

  for (int i = tid; i < 16 * LDH; i += kT) { hAb[0][i] = 0; hBb[0][i] = 0; }

  // One weight matrix per wave; 4 gate tiles x 8 K-frags = 32 short8.
  // Gate col (JAX i,f,g,o order): t*256 + slice*32 + U*16 + n16.
  const float* mat = (L == 0) ? (R == 0 ? w_ih0 : w_hh0)
                              : (R == 0 ? w_hh1 : w_ih1);
  short8 wB[4][8];
  {
#pragma unroll
    for (int t = 0; t < 4; ++t) {
      const int gcol = t * kH + slice * 32 + U * 16 + n16;
      const float* wp = mat + (size_t)gcol * kH;
#pragma unroll
      for (int kk = 0; kk < 8; ++kk) {
        const float* p4 = wp + kk * 32 + quad * 8;
        const float4 f0 = *(const float4*)p4;
        const float4 f1 = *(const float4*)(p4 + 4);
        short8 v;
        v[0] = f2bf(f0.x); v[1] = f2bf(f0.y); v[2] = f2bf(f0.z); v[3] = f2bf(f0.w);
        v[4] = f2bf(f1.x); v[5] = f2bf(f1.y); v[6] = f2bf(f1.z); v[7] = f2bf(f1.w);
        wB[t][kk] = v;
      }
    }
  }
  // L0R0 also owns embedding weights for emb cols [U*128, +128).
  short8 wE[8];
  float bembv[8];
  if (L == 0 && R == 0) {
#pragma unroll
    for (int i = 0; i < 8; ++i) {
      const int col = U * 128 + i * 16 + n16;
      short8 v;
#pragma unroll
      for (int j = 0; j < 8; ++j) {
        const int k = quad * 8 + j;
        v[j] = (k < kI) ? f2bf(W_emb[col * kI + k]) : (short)0;
      }
      wE[i] = v;
      bembv[i] = b_emb[col];
    }
  }
  // Elem (R1): lane owns unit ecol, rows quad*4+r (r=0..3); all 4 gates local.
  const int ecol = slice * 32 + U * 16 + n16;
  float bi[4] = {0.f, 0.f, 0.f, 0.f};
  if (R == 1) {
    const float* bih = L ? b_ih1 : b_ih0;
    const float* bhh = L ? b_hh1 : b_hh0;
#pragma unroll
    for (int t = 0; t < 4; ++t) bi[t] = bih[t * kH + ecol] + bhh[t * kH + ecol];
  }
  f32x4 cst = {0.f, 0.f, 0.f, 0.f};  // c-state (4 rows) per R1 lane

#define EMB8(BUF, T)                                                        \
  {                                                                         \
    const float* xr = x + ((size_t)(b0 + n16) * kS + (T)) * kI;             \
    short8 xa;                                                              \
    _Pragma("unroll")                                                       \
    for (int j = 0; j < 8; ++j) {                                           \
      const int k = quad * 8 + j;                                           \
      xa[j] = (k < kI) ? f2bf(xr[k]) : (short)0;                            \
    }                                                                       \
    _Pragma("unroll")                                                       \
    for (int i = 0; i < 8; ++i) {                                           \
      f32x4 zz = {0.f, 0.f, 0.f, 0.f};                                      \
      f32x4 e = MFMA16(xa, wE[i], zz);                                      \
      const int col = U * 128 + i * 16 + n16;                               \
      _Pragma("unroll")                                                     \
      for (int r = 0; r < 4; ++r) {                                         \
        float v = e[r] + bembv[i];                                          \
        v = v > 0.f ? v : 0.f;                                              \
        (BUF)[(quad * 4 + r) * LDH + col] = f2bf(v);                        \
      }                                                                     \
    }                                                                       \
  }

  // -------- prologue: emb(0)->embL[0], emb(1)->embL[1]; z(0)->gZ[0] --------
  if (L == 0 && R == 0) { EMB8(embL[0], 0) EMB8(embL[1], 1) }
  __syncthreads();
  if (L == 0 && R == 0) {
    f32x4 a0 = {0.f,0.f,0.f,0.f}, a1 = a0, a2 = a0, a3 = a0;
#pragma unroll
    for (int kk = 0; kk < 8; ++kk) {
      const short8 e = *(const short8*)&embL[0][n16 * LDH + kk * 32 + quad * 8];
      a0 = MFMA16(e, wB[0][kk], a0);
      a1 = MFMA16(e, wB[1][kk], a1);
      a2 = MFMA16(e, wB[2][kk], a2);
      a3 = MFMA16(e, wB[3][kk], a3);
    }
    const int gzb = (U * 4) * 256 + lane * 4;  // par=0
    *(f32x4*)&gZ[gzb +   0] = a0;
    *(f32x4*)&gZ[gzb + 256] = a1;
    *(f32x4*)&gZ[gzb + 512] = a2;
    *(f32x4*)&gZ[gzb + 768] = a3;
    // phase-0 B_mid orders these writes before L0R1's read
  }

  unsigned char* const flB = flags + (size_t)btile * kS * 32;
  const uint64_t kOnes = 0x0101010101010101ULL;

  for (int p = 0; p <= kS; ++p) {
    const int par = p & 1;
    f32x4 acc0 = {0.f,0.f,0.f,0.f}, acc1 = acc0, acc2 = acc0, acc3 = acc0;

    // ================= section 1: per-role MFMA work =================
    if (R == 0) {
      if (L == 1) {
        // hB(h1(p-2)) @ w_hh1 partial -> gP (needed at B_mid this phase)
        const short* hb = hBb[par];
#pragma unroll
        for (int kk = 0; kk < 8; ++kk) {
          const short8 e = *(const short8*)&hb[n16 * LDH + kk * 32 + quad * 8];
          acc0 = MFMA16(e, wB[0][kk], acc0);
          acc1 = MFMA16(e, wB[1][kk], acc1);
          acc2 = MFMA16(e, wB[2][kk], acc2);
          acc3 = MFMA16(e, wB[3][kk], acc3);
        }
        const int gpb = (U * 4) * 256 + lane * 4;
        *(f32x4*)&gP[gpb +   0] = acc0;
        *(f32x4*)&gP[gpb + 256] = acc1;
        *(f32x4*)&gP[gpb + 512] = acc2;
        *(f32x4*)&gP[gpb + 768] = acc3;
      } else {
        // L0R0: prefetch work for NEXT phases (no B_mid dependency)
        if (p + 1 < kS) {
          const short* eb = embL[par ^ 1];  // emb(p+1), written phase p-1
#pragma unroll
          for (int kk = 0; kk < 8; ++kk) {
            const short8 e = *(const short8*)&eb[n16 * LDH + kk * 32 + quad * 8];
            acc0 = MFMA16(e, wB[0][kk], acc0);
            acc1 = MFMA16(e, wB[1][kk], acc1);
            acc2 = MFMA16(e, wB[2][kk], acc2);
            acc3 = MFMA16(e, wB[3][kk], acc3);
          }
          const int gzb = (((par ^ 1) * 2 + U) * 4) * 256 + lane * 4;
          *(f32x4*)&gZ[gzb +   0] = acc0;
          *(f32x4*)&gZ[gzb + 256] = acc1;
          *(f32x4*)&gZ[gzb + 512] = acc2;
          *(f32x4*)&gZ[gzb + 768] = acc3;
        }
        if (p + 2 < kS) { EMB8(embL[par], p + 2) }  // emb(p+2) -> embL[par]
      }
    } else {
      // R1: hA(h0(p-1)) partial (w_hh0 for L0, w_ih1 for L1)
      const bool act = (L == 0) ? (p < kS) : (p >= 1);
      if (act) {
        const short* ha = hAb[par];
#pragma unroll
        for (int kk = 0; kk < 8; ++kk) {
          const short8 e = *(const short8*)&ha[n16 * LDH + kk * 32 + quad * 8];
          acc0 = MFMA16(e, wB[0][kk], acc0);
          acc1 = MFMA16(e, wB[1][kk], acc1);
          acc2 = MFMA16(e, wB[2][kk], acc2);
          acc3 = MFMA16(e, wB[3][kk], acc3);
        }
      }
    }
    __syncthreads();  // B_mid: gP (and prologue gZ) visible to R1

    // ============ section 2: R1 combine+elem+publish  ||  R0 spin+gather ============
    if (R == 1) {
      const bool act = (L == 0) ? (p < kS) : (p >= 1);
      if (act) {
        const float* part = (L == 0) ? &gZ[((par * 2 + U) * 4) * 256 + lane * 4]
                                     : &gP[(U * 4) * 256 + lane * 4];
        acc0 += *(const f32x4*)(part +   0);
        acc1 += *(const f32x4*)(part + 256);
        acc2 += *(const f32x4*)(part + 512);
        acc3 += *(const f32x4*)(part + 768);
        unsigned short* hex = (L == 0) ? h0ex : h1ex;
        const size_t hbase = (size_t)par * kBH;
#pragma unroll
        for (int r = 0; r < 4; ++r) {
          const float iv = acc0[r] + bi[0];
          const float fv = acc1[r] + bi[1];
          const float gv = acc2[r] + bi[2];
          const float ov = acc3[r] + bi[3];
          const float c = fast_sigmoid(fv) * cst[r] + fast_sigmoid(iv) * fast_tanh(gv);
          cst[r] = c;
          const float h = fast_sigmoid(ov) * fast_tanh(c);
          const int row = b0 + quad * 4 + r;
          __hip_atomic_store(&hex[hbase + (size_t)row * kH + ecol],
                             (unsigned short)f2bf(h),
                             __ATOMIC_RELAXED, __HIP_MEMORY_SCOPE_AGENT);
          if ((L == 0 && p == kS - 1) || (L == 1 && p == kS)) {
            dout[OUT_H + (size_t)L * kBH + (size_t)row * kH + ecol] = h;
            dout[OUT_C + (size_t)L * kBH + (size_t)row * kH + ecol] = c;
          }
        }
      }
      if (p < kS) {
        // own stores drained -> publish this wave's slot (p=0 L1: pre-zeroed data)
        asm volatile("s_waitcnt vmcnt(0)" ::: "memory");
        if (lane == 0)
          __hip_atomic_store(flB + (size_t)p * 32 + slice * 4 + L * 2 + U,
                             (unsigned char)1,
                             __ATOMIC_RELAXED, __HIP_MEMORY_SCOPE_AGENT);
      }
    } else if (p < kS) {
      // R0 waves: spin for all 32 slots of phase p (escalating backoff),
      // then gather into [par^1]
      const uint64_t* f64 = (const uint64_t*)(flB + (size_t)p * 32);
      int spins = 0;
      for (;;) {
        const uint64_t v0 = __hip_atomic_load(f64 + 0, __ATOMIC_RELAXED, __HIP_MEMORY_SCOPE_AGENT);
        const uint64_t v1 = __hip_atomic_load(f64 + 1, __ATOMIC_RELAXED, __HIP_MEMORY_SCOPE_AGENT);
        const uint64_t v2 = __hip_atomic_load(f64 + 2, __ATOMIC_RELAXED, __HIP_MEMORY_SCOPE_AGENT);
        const uint64_t v3 = __hip_atomic_load(f64 + 3, __ATOMIC_RELAXED, __HIP_MEMORY_SCOPE_AGENT);
        if (v0 == kOnes && v1 == kOnes && v2 == kOnes && v3 == kOnes) break;
        if (++spins > 256) __builtin_amdgcn_s_sleep(8);
        else               __builtin_amdgcn_s_sleep(1);
      }
      const int rtid = (wave >> 1) * 64 + lane;  // R0 waves 0,2,4,6 -> 0..255
      const int rr = rtid >> 4;
      const int cc = (rtid & 15) * 16;
      const size_t base = (size_t)par * kBH + (size_t)(b0 + rr) * kH + cc;
      const uint64_t* s0 = (const uint64_t*)&h0ex[base];
      const uint64_t* s1 = (const uint64_t*)&h1ex[base];
      const uint64_t ga0 = __hip_atomic_load(s0 + 0, __ATOMIC_RELAXED, __HIP_MEMORY_SCOPE_AGENT);
      const uint64_t ga1 = __hip_atomic_load(s0 + 1, __ATOMIC_RELAXED, __HIP_MEMORY_SCOPE_AGENT);
      const uint64_t ga2 = __hip_atomic_load(s0 + 2, __ATOMIC_RELAXED, __HIP_MEMORY_SCOPE_AGENT);
      const uint64_t ga3 = __hip_atomic_load(s0 + 3, __ATOMIC_RELAXED, __HIP_MEMORY_SCOPE_AGENT);
      const uint64_t gb0 = __hip_atomic_load(s1 + 0, __ATOMIC_RELAXED, __HIP_MEMORY_SCOPE_AGENT);
      const uint64_t gb1 = __hip_atomic_load(s1 + 1, __ATOMIC_RELAXED, __HIP_MEMORY_SCOPE_AGENT);
      const uint64_t gb2 = __hip_atomic_load(s1 + 2, __ATOMIC_RELAXED, __HIP_MEMORY_SCOPE_AGENT);
      const uint64_t gb3 = __hip_atomic_load(s1 + 3, __ATOMIC_RELAXED, __HIP_MEMORY_SCOPE_AGENT);
      uint64_t* dA = (uint64_t*)&hAb[par ^ 1][rr * LDH + cc];
      uint64_t* dB = (uint64_t*)&hBb[par ^ 1][rr * LDH + cc];
      dA[0] = ga0; dA[1] = ga1; dA[2] = ga2; dA[3] = ga3;
      dB[0] = gb0; dB[1] = gb1; dB[2] = gb2; dB[3] = gb3;
    }
    __syncthreads();  // B_end: [par^1] buffers + gZ/embL ready for next phase
  }
#undef EMB8
}

// LayerNorm + MLP head, exact fp32. One wave per batch row.
__global__ __launch_bounds__(64) void head_kernel(
    const float* __restrict__ h1last, const float* __restrict__ mask,
    const float* __restrict__ ln_g, const float* __restrict__ ln_b,
    const float* __restrict__ w1, const float* __restrict__ b1,
    const float* __restrict__ w2, const float* __restrict__ b2,
    float* __restrict__ out)
{
  const int r = blockIdx.x;
  const int lane = threadIdx.x;
  __shared__ float ns[kH];
  __shared__ float hd[32];
  const float4 v = *(const float4*)&h1last[r * kH + lane * 4];
  float vv[4] = {v.x, v.y, v.z, v.w};
  float s = vv[0] + vv[1] + vv[2] + vv[3];
#pragma unroll
  for (int off = 32; off > 0; off >>= 1) s += __shfl_xor(s, off, 64);
  const float mean = s * (1.f / kH);
  float q = 0.f;
#pragma unroll
  for (int j = 0; j < 4; ++j) { const float d = vv[j] - mean; q += d * d; }
#pragma unroll
  for (int off = 32; off > 0; off >>= 1) q += __shfl_xor(q, off, 64);
  const float rstd = rsqrtf(q * (1.f / kH) + 1e-5f);
#pragma unroll
  for (int j = 0; j < 4; ++j) {
    const int c = lane * 4 + j;
    ns[c] = (vv[j] - mean) * rstd * ln_g[c] + ln_b[c];
  }
  __syncthreads();
  if (lane < 32) {
    float a = b1[lane];
    const float* wr = w1 + lane * kH;
    for (int k = 0; k < kH; ++k) a += ns[k] * wr[k];
    hd[lane] = a > 0.f ? a : 0.f;
  }
  __syncthreads();
  if (lane < kA) {
    float a = b2[lane];
    const float* wr = w2 + lane * 32;
#pragma unroll
    for (int k = 0; k < 32; ++k) a += hd[k] * wr[k];
    a += (1.f - mask[r * kA + lane]) * (-1e9f);
    out[r * kA + lane] = a;
  }
}

extern "C" void kernel_launch(void* const* d_in, const int* in_sizes, int n_in,
                              void* d_out, int out_size, void* d_ws, size_t ws_size,
                              hipStream_t stream)
{
  (void)in_sizes; (void)n_in; (void)out_size; (void)ws_size;
  const float* x     = (const float*)d_in[0];
  const float* mask  = (const float*)d_in[1];
  const float* W_emb = (const float*)d_in[2];
  const float* b_emb = (const float*)d_in[3];
  const float* w_ih0 = (const float*)d_in[4];
  const float* w_hh0 = (const float*)d_in[5];
  const float* b_ih0 = (const float*)d_in[6];
  const float* b_hh0 = (const float*)d_in[7];
  const float* w_ih1 = (const float*)d_in[8];
  const float* w_hh1 = (const float*)d_in[9];
  const float* b_ih1 = (const float*)d_in[10];
  const float* b_hh1 = (const float*)d_in[11];
  const float* ln_g  = (const float*)d_in[12];
  const float* ln_b  = (const float*)d_in[13];
  const float* w1    = (const float*)d_in[14];
  const float* b1    = (const float*)d_in[15];
  const float* w2    = (const float*)d_in[16];
  const float* b2    = (const float*)d_in[17];
  float* out = (float*)d_out;

  // ws layout: h0ex[2][512][256] bf16 | h1ex[2][512][256] bf16
  //            | flags[32 btiles][256 phases][32 u8 slots]
  unsigned short* h0ex = (unsigned short*)d_ws;
  unsigned short* h1ex = h0ex + 2 * kBH;
  unsigned char* flags = (unsigned char*)(h1ex + 2 * kBH);
  const size_t flag_bytes = (size_t)kNB * kS * 32;  // 256 KiB

  // flags must start 0; h1ex parity-0 must be zeros (h1(-1)=0, gathered at p=0).
  hipMemsetAsync(flags, 0, flag_bytes, stream);
  hipMemsetAsync(h1ex, 0, (size_t)kBH * sizeof(unsigned short), stream);

  lstm_scan_kernel<<<dim3(kNB * kNS), dim3(kT), 0, stream>>>(
      x, W_emb, b_emb, w_ih0, w_hh0, b_ih0, b_hh0, w_ih1, w_hh1, b_ih1, b_hh1,
      h0ex, h1ex, flags, out);

  head_kernel<<<dim3(kB), dim3(64), 0, stream>>>(
      out + OUT_H + kBH, mask, ln_g, ln_b, w1, b1, w2, b2, out);
}

// Round 8
// 1194.760 us; speedup vs baseline: 1.6177x; 1.6177x over previous
//
#include <hip/hip_runtime.h>
#include <cstdint>
#include <cstddef>

typedef __attribute__((ext_vector_type(8))) short short8;
typedef __attribute__((ext_vector_type(4))) float f32x4;

#define MFMA16(a, b, c) __builtin_amdgcn_mfma_f32_16x16x32_bf16((a), (b), (c), 0, 0, 0)

constexpr int kB = 512, kS = 256, kI = 12, kH = 256, kA = 9;
constexpr int kNS = 8;    // hidden slices per batch tile (32 h-units each)
constexpr int kNB = 32;   // batch tiles (16 rows each)
constexpr int kT  = 512;  // block size: 8 waves
constexpr int LDH = 264;  // padded LDS stride (bf16) for K=256 operand tiles
constexpr int LDG = 132;  // padded LDS stride (fp32) for 16x128 gate tiles
constexpr int kBH = kB * kH;

// d_out layout (floats): [logits 512*9][h0 512*256][h1 512*256][c0 512*256][c1 512*256]
constexpr int OUT_H = kB * kA;              // 4608
constexpr int OUT_C = OUT_H + 2 * kBH;      // 266752

__device__ __forceinline__ short f2bf(float f) {  // RTNE fp32 -> bf16 bits
  uint32_t u = __float_as_uint(f);
  u += 0x7fffu + ((u >> 16) & 1u);
  return (short)(u >> 16);
}
__device__ __forceinline__ float fast_sigmoid(float v) {
  return __builtin_amdgcn_rcpf(1.f + __expf(-v));
}
__device__ __forceinline__ float fast_tanh(float v) {
  return 2.f * __builtin_amdgcn_rcpf(1.f + __expf(-2.f * v)) - 1.f;
}

// R12 = R4/R7 skeleton with two pure DELETIONS (no new machinery):
//  (1) L-split mapping: wave (L=w&1, P=w>>1) computes gate P (units 0..31)
//      of ONE layer -> reads 2 A-operands (16 ds_read_b128) instead of 3
//      (24). Per-CU head reads 192->128; each read feeds 2 MFMAs.
//      (L0: emb@w_ih0 + hA@w_hh0; L1: hA@w_ih1 + hB@w_hh1.)
//  (2) B2 removed: per-wave u8 flag slots (8 slices x 8 waves = 64/phase,
//      plain relaxed stores). Each wave drains its OWN stores (vmcnt(0))
//      and publishes its own slot -> no block-wide drain barrier, no
//      serialized RMW chain; fast waves flow into emb/spin/gather early.
//      Phase barriers: 3 -> 2 (B1 gate-ready, B5 post-gather).
// Safety: embL written (window) only after B1 of same phase (no head
// readers left); gL written (head) only after B5 of prev phase (no elem
// readers left); hA/hB written (gather) only after spin, readers (head)
// separated by B5. All cross-wave LDS deps ordered by B1/B5.
// R11's lesson applied: keep all 8 waves on every section (homogeneous).
__global__ __launch_bounds__(kT) void lstm_scan_kernel(
    const float* __restrict__ x,
    const float* __restrict__ W_emb, const float* __restrict__ b_emb,
    const float* __restrict__ w_ih0, const float* __restrict__ w_hh0,
    const float* __restrict__ b_ih0, const float* __restrict__ b_hh0,
    const float* __restrict__ w_ih1, const float* __restrict__ w_hh1,
    const float* __restrict__ b_ih1, const float* __restrict__ b_hh1,
    unsigned short* __restrict__ h0ex, unsigned short* __restrict__ h1ex,
    unsigned char* __restrict__ flags,
    float* __restrict__ dout)
{
  const int tid   = threadIdx.x;
  const int btile = blockIdx.x & (kNB - 1);  // bid%8==btile%8 -> slices share an XCD
  const int slice = blockIdx.x >> 5;
  const int b0    = btile * 16;
  const int lane  = tid & 63;
  const int wave  = tid >> 6;
  const int n16   = lane & 15;
  const int quad  = lane >> 4;
  const int L     = wave & 1;   // layer
  const int P     = wave >> 1;  // gate index 0..3 (i,f,g,o)

  __shared__ short embL[16 * LDH];   // emb(p) (bf16) A-operand
  __shared__ short hA[16 * LDH];     // h0(p-1) — layer0 recurrence AND layer1 input
  __shared__ short hB[16 * LDH];     // h1(p-2) — layer1 recurrence
  __shared__ float gL0[16 * LDG];    // layer0 gates 16 x 128 fp32 (col = gate*32+unit)
  __shared__ float gL1[16 * LDG];    // layer1 gates 16 x 128 fp32

  for (int i = tid; i < 16 * LDH; i += kT) { hA[i] = 0; hB[i] = 0; }

  // Weight B-fragments: wave (L,P) owns gate P, units [0,32) of layer L ->
  // 2 operand-matrices x 2 unit-half tiles x 8 K-frags = 32 short8.
  // Global gate row (JAX i,f,g,o): P*256 + slice*32 + t*16 + n16.
  const float* m0 = L ? w_ih1 : w_ih0;  // pairs with op1 (hA : embL)
  const float* m1 = L ? w_hh1 : w_hh0;  // pairs with op2 (hB : hA)
  short8 wB[2][2][8];
  {
    const float* Wm[2] = { m0, m1 };
#pragma unroll
    for (int m = 0; m < 2; ++m) {
#pragma unroll
      for (int t = 0; t < 2; ++t) {
        const int gcol = P * kH + slice * 32 + t * 16 + n16;
        const float* wp = Wm[m] + (size_t)gcol * kH;
#pragma unroll
        for (int kk = 0; kk < 8; ++kk) {
          const float* p4 = wp + kk * 32 + quad * 8;
          const float4 f0 = *(const float4*)p4;
          const float4 f1 = *(const float4*)(p4 + 4);
          short8 v;
          v[0] = f2bf(f0.x); v[1] = f2bf(f0.y); v[2] = f2bf(f0.z); v[3] = f2bf(f0.w);
          v[4] = f2bf(f1.x); v[5] = f2bf(f1.y); v[6] = f2bf(f1.z); v[7] = f2bf(f1.w);
          wB[m][t][kk] = v;
        }
      }
    }
  }
  // Embedding weights (K=12 zero-padded to 32). Wave computes emb cols [wave*32, +32).
  short8 wE[2];
  float bembv[2];
#pragma unroll
  for (int i = 0; i < 2; ++i) {
    const int col = wave * 32 + i * 16 + n16;
    short8 v;
#pragma unroll
    for (int j = 0; j < 8; ++j) {
      const int k = quad * 8 + j;
      v[j] = (k < kI) ? f2bf(W_emb[col * kI + k]) : (short)0;
    }
    wE[i] = v;
    bembv[i] = b_emb[col];
  }
  // Elementwise mapping: thread = (row=tid>>5, col=tid&31); 1 hidden unit per layer.
  const int erow = tid >> 5;
  const int ec   = tid & 31;
  const int ecol = slice * 32 + ec;
  float bi0[4], bi1[4];
#pragma unroll
  for (int g = 0; g < 4; ++g) {
    bi0[g] = b_ih0[g * kH + ecol] + b_hh0[g * kH + ecol];
    bi1[g] = b_ih1[g * kH + ecol] + b_hh1[g * kH + ecol];
  }
  float c0v = 0.f, c1v = 0.f;

  // -------- prologue: emb(0) from direct global x loads --------
  {
    const float* xr = x + (size_t)(b0 + n16) * kS * kI;  // t = 0
    short8 xa;
#pragma unroll
    for (int j = 0; j < 8; ++j) {
      const int k = quad * 8 + j;
      xa[j] = (k < kI) ? f2bf(xr[k]) : (short)0;
    }
#pragma unroll
    for (int i = 0; i < 2; ++i) {
      f32x4 z = {0.f, 0.f, 0.f, 0.f};
      f32x4 e = MFMA16(xa, wE[i], z);
      const int col = wave * 32 + i * 16 + n16;
#pragma unroll
      for (int r = 0; r < 4; ++r) {
        float v = e[r] + bembv[i];
        v = v > 0.f ? v : 0.f;
        embL[(quad * 4 + r) * LDH + col] = f2bf(v);  // C-layout: row=quad*4+r
      }
    }
  }
  __syncthreads();

  unsigned char* const flB = flags + (size_t)btile * kS * 64;
  const uint64_t kOnes = 0x0101010101010101ULL;

  for (int p = 0; p <= kS; ++p) {
    const int par = p & 1;

    // ---- head: wave (L,P) -> gate P of layer L, both unit-halves.
    //      16 ds_read_b128 (each feeds 2 MFMAs), 32 MFMAs. ----
    {
      const short* op1 = L ? hA : embL;
      const short* op2 = L ? hB : hA;
      f32x4 aA = {0.f,0.f,0.f,0.f}, aB = aA;
#pragma unroll
      for (int kk = 0; kk < 8; ++kk) {
        const short8 e = *(const short8*)&op1[n16 * LDH + kk * 32 + quad * 8];
        aA = MFMA16(e, wB[0][0][kk], aA);
        aB = MFMA16(e, wB[0][1][kk], aB);
      }
#pragma unroll
      for (int kk = 0; kk < 8; ++kk) {
        const short8 e = *(const short8*)&op2[n16 * LDH + kk * 32 + quad * 8];
        aA = MFMA16(e, wB[1][0][kk], aA);
        aB = MFMA16(e, wB[1][1][kk], aB);
      }
      float* gldst = L ? gL1 : gL0;
      const int colA = P * 32 + n16;        // gate-major: gate*32 + unit
      const int colB = colA + 16;
#pragma unroll
      for (int r = 0; r < 4; ++r) {
        gldst[(quad * 4 + r) * LDG + colA] = aA[r];
        gldst[(quad * 4 + r) * LDG + colB] = aB[r];
      }
    }
    __syncthreads();  // B1: gate tiles ready

    // ---- elementwise layer0 (step p), guarded ----
    if (p < kS) {
      const float iv = gL0[erow * LDG +       ec] + bi0[0];
      const float fv = gL0[erow * LDG +  32 + ec] + bi0[1];
      const float gv = gL0[erow * LDG +  64 + ec] + bi0[2];
      const float ov = gL0[erow * LDG +  96 + ec] + bi0[3];
      const float c = fast_sigmoid(fv) * c0v + fast_sigmoid(iv) * fast_tanh(gv);
      c0v = c;
      const float h = fast_sigmoid(ov) * fast_tanh(c);
      unsigned short* dst = &h0ex[(size_t)par * kBH + (size_t)(b0 + erow) * kH + ecol];
      __hip_atomic_store(dst, (unsigned short)f2bf(h), __ATOMIC_RELAXED, __HIP_MEMORY_SCOPE_AGENT);
      if (p == kS - 1) {
        dout[OUT_H + (size_t)(b0 + erow) * kH + ecol] = h;
        dout[OUT_C + (size_t)(b0 + erow) * kH + ecol] = c;
      }
    }
    // ---- elementwise layer1 (step p-1), guarded ----
    if (p >= 1) {
      const float iv = gL1[erow * LDG +       ec] + bi1[0];
      const float fv = gL1[erow * LDG +  32 + ec] + bi1[1];
      const float gv = gL1[erow * LDG +  64 + ec] + bi1[2];
      const float ov = gL1[erow * LDG +  96 + ec] + bi1[3];
      const float c = fast_sigmoid(fv) * c1v + fast_sigmoid(iv) * fast_tanh(gv);
      c1v = c;
      const float h = fast_sigmoid(ov) * fast_tanh(c);
      unsigned short* dst = &h1ex[(size_t)par * kBH + (size_t)(b0 + erow) * kH + ecol];
      __hip_atomic_store(dst, (unsigned short)f2bf(h), __ATOMIC_RELAXED, __HIP_MEMORY_SCOPE_AGENT);
      if (p == kS) {
        dout[OUT_H + kBH + (size_t)(b0 + erow) * kH + ecol] = h;
        dout[OUT_C + kBH + (size_t)(b0 + erow) * kH + ecol] = c;
      }
    }

    if (p < kS) {
      // ---- per-wave drain + publish (replaces B2 + serialized RMW) ----
      asm volatile("s_waitcnt vmcnt(0)" ::: "memory");
      if (lane == 0)
        __hip_atomic_store(flB + (size_t)p * 64 + slice * 8 + wave,
                           (unsigned char)1,
                           __ATOMIC_RELAXED, __HIP_MEMORY_SCOPE_AGENT);

      // ---- emb(p+1): overlaps flag/data propagation through the IC.
      //      Safe without B2: all waves passed B1, so no head reader of
      //      embL remains this phase; elem does not read embL. ----
      if (p + 1 < kS) {
        const float* xr = x + ((size_t)(b0 + n16) * kS + (p + 1)) * kI;
        short8 xa;
#pragma unroll
        for (int j = 0; j < 8; ++j) {
          const int k = quad * 8 + j;
          xa[j] = (k < kI) ? f2bf(xr[k]) : (short)0;
        }
#pragma unroll
        for (int i = 0; i < 2; ++i) {
          f32x4 z = {0.f, 0.f, 0.f, 0.f};
          f32x4 e = MFMA16(xa, wE[i], z);
          const int col = wave * 32 + i * 16 + n16;
#pragma unroll
          for (int r = 0; r < 4; ++r) {
            float v = e[r] + bembv[i];
            v = v > 0.f ? v : 0.f;
            embL[(quad * 4 + r) * LDH + col] = f2bf(v);
          }
        }
      }

      // ---- per-wave spin on the 64 u8 slots (8 x u64, uniform exit) ----
      {
        const uint64_t* f64 = (const uint64_t*)(flB + (size_t)p * 64);
        for (;;) {
          const uint64_t v0 = __hip_atomic_load(f64 + 0, __ATOMIC_RELAXED, __HIP_MEMORY_SCOPE_AGENT);
          const uint64_t v1 = __hip_atomic_load(f64 + 1, __ATOMIC_RELAXED, __HIP_MEMORY_SCOPE_AGENT);
          const uint64_t v2 = __hip_atomic_load(f64 + 2, __ATOMIC_RELAXED, __HIP_MEMORY_SCOPE_AGENT);
          const uint64_t v3 = __hip_atomic_load(f64 + 3, __ATOMIC_RELAXED, __HIP_MEMORY_SCOPE_AGENT);
          const uint64_t v4 = __hip_atomic_load(f64 + 4, __ATOMIC_RELAXED, __HIP_MEMORY_SCOPE_AGENT);
          const uint64_t v5 = __hip_atomic_load(f64 + 5, __ATOMIC_RELAXED, __HIP_MEMORY_SCOPE_AGENT);
          const uint64_t v6 = __hip_atomic_load(f64 + 6, __ATOMIC_RELAXED, __HIP_MEMORY_SCOPE_AGENT);
          const uint64_t v7 = __hip_atomic_load(f64 + 7, __ATOMIC_RELAXED, __HIP_MEMORY_SCOPE_AGENT);
          if (v0 == kOnes && v1 == kOnes && v2 == kOnes && v3 == kOnes &&
              v4 == kOnes && v5 == kOnes && v6 == kOnes && v7 == kOnes)
            break;
          __builtin_amdgcn_s_sleep(1);
        }
      }

      // ---- gather h0(p) -> hA, h1(p-1) -> hB (relaxed u64 loads) ----
      {
        const int rr = tid >> 5;
        const int cc = (tid & 31) * 8;
        const size_t base = (size_t)par * kBH + (size_t)(b0 + rr) * kH + cc;
        const uint64_t* s0 = (const uint64_t*)&h0ex[base];
        const uint64_t* s1 = (const uint64_t*)&h1ex[base];
        uint64_t va0 = __hip_atomic_load(s0 + 0, __ATOMIC_RELAXED, __HIP_MEMORY_SCOPE_AGENT);
        uint64_t va1 = __hip_atomic_load(s0 + 1, __ATOMIC_RELAXED, __HIP_MEMORY_SCOPE_AGENT);
        uint64_t vb0 = __hip_atomic_load(s1 + 0, __ATOMIC_RELAXED, __HIP_MEMORY_SCOPE_AGENT);
        uint64_t vb1 = __hip_atomic_load(s1 + 1, __ATOMIC_RELAXED, __HIP_MEMORY_SCOPE_AGENT);
        uint64_t* dA = (uint64_t*)&hA[rr * LDH + cc];
        uint64_t* dB = (uint64_t*)&hB[rr * LDH + cc];
        dA[0] = va0; dA[1] = va1;
        dB[0] = vb0; dB[1] = vb1;
      }
      __syncthreads();  // B5: hA/hB/embL ready for next phase's head
    }
  }
}

// LayerNorm + MLP head, exact fp32. One wave per batch row.
__global__ __launch_bounds__(64) void head_kernel(
    const float* __restrict__ h1last, const float* __restrict__ mask,
    const float* __restrict__ ln_g, const float* __restrict__ ln_b,
    const float* __restrict__ w1, const float* __restrict__ b1,
    const float* __restrict__ w2, const float* __restrict__ b2,
    float* __restrict__ out)
{
  const int r = blockIdx.x;
  const int lane = threadIdx.x;
  __shared__ float ns[kH];
  __shared__ float hd[32];
  const float4 v = *(const float4*)&h1last[r * kH + lane * 4];
  float vv[4] = {v.x, v.y, v.z, v.w};
  float s = vv[0] + vv[1] + vv[2] + vv[3];
#pragma unroll
  for (int off = 32; off > 0; off >>= 1) s += __shfl_xor(s, off, 64);
  const float mean = s * (1.f / kH);
  float q = 0.f;
#pragma unroll
  for (int j = 0; j < 4; ++j) { const float d = vv[j] - mean; q += d * d; }
#pragma unroll
  for (int off = 32; off > 0; off >>= 1) q += __shfl_xor(q, off, 64);
  const float rstd = rsqrtf(q * (1.f / kH) + 1e-5f);
#pragma unroll
  for (int j = 0; j < 4; ++j) {
    const int c = lane * 4 + j;
    ns[c] = (vv[j] - mean) * rstd * ln_g[c] + ln_b[c];
  }
  __syncthreads();
  if (lane < 32) {
    float a = b1[lane];
    const float* wr = w1 + lane * kH;
    for (int k = 0; k < kH; ++k) a += ns[k] * wr[k];
    hd[lane] = a > 0.f ? a : 0.f;
  }
  __syncthreads();
  if (lane < kA) {
    float a = b2[lane];
    const float* wr = w2 + lane * 32;
#pragma unroll
    for (int k = 0; k < 32; ++k) a += hd[k] * wr[k];
    a += (1.f - mask[r * kA + lane]) * (-1e9f);
    out[r * kA + lane] = a;
  }
}

extern "C" void kernel_launch(void* const* d_in, const int* in_sizes, int n_in,
                              void* d_out, int out_size, void* d_ws, size_t ws_size,
                              hipStream_t stream)
{
  (void)in_sizes; (void)n_in; (void)out_size; (void)ws_size;
  const float* x     = (const float*)d_in[0];
  const float* mask  = (const float*)d_in[1];
  const float* W_emb = (const float*)d_in[2];
  const float* b_emb = (const float*)d_in[3];
  const float* w_ih0 = (const float*)d_in[4];
  const float* w_hh0 = (const float*)d_in[5];
  const float* b_ih0 = (const float*)d_in[6];
  const float* b_hh0 = (const float*)d_in[7];
  const float* w_ih1 = (const float*)d_in[8];
  const float* w_hh1 = (const float*)d_in[9];
  const float* b_ih1 = (const float*)d_in[10];
  const float* b_hh1 = (const float*)d_in[11];
  const float* ln_g  = (const float*)d_in[12];
  const float* ln_b  = (const float*)d_in[13];
  const float* w1    = (const float*)d_in[14];
  const float* b1    = (const float*)d_in[15];
  const float* w2    = (const float*)d_in[16];
  const float* b2    = (const float*)d_in[17];
  float* out = (float*)d_out;

  // ws layout: h0ex[2][512][256] bf16 | h1ex[2][512][256] bf16
  //            | flags[32 btiles][256 phases][64 u8 slots]
  unsigned short* h0ex = (unsigned short*)d_ws;
  unsigned short* h1ex = h0ex + 2 * kBH;
  unsigned char* flags = (unsigned char*)(h1ex + 2 * kBH);
  const size_t flag_bytes = (size_t)kNB * kS * 64;  // 512 KiB

  // flags must start 0; h1ex parity-0 must be zeros (h1(-1)=0, gathered at p=0).
  hipMemsetAsync(flags, 0, flag_bytes, stream);
  hipMemsetAsync(h1ex, 0, (size_t)kBH * sizeof(unsigned short), stream);

  lstm_scan_kernel<<<dim3(kNB * kNS), dim3(kT), 0, stream>>>(
      x, W_emb, b_emb, w_ih0, w_hh0, b_ih0, b_hh0, w_ih1, w_hh1, b_ih1, b_hh1,
      h0ex, h1ex, flags, out);

  head_kernel<<<dim3(kB), dim3(64), 0, stream>>>(
      out + OUT_H + kBH, mask, ln_g, ln_b, w1, b1, w2, b2, out);
}